// Round 13
// baseline (142.689 us; speedup 1.0000x reference)
//
#include <hip/hip_runtime.h>
#include <float.h>

#define VOCAB 8192
#define DIM 64
#define NQ 32768
#define CHUNK 64                    // centroids staged per LDS buffer
#define THREADS 256
#define QPB 128                     // queries per block (32 per wave)
#define NSLICE 4

typedef __attribute__((ext_vector_type(8))) _Float16 half8;
typedef __attribute__((ext_vector_type(16))) float f32x16;

#define LO_SCALE 4096.0f
#define LO_INV   2.44140625e-4f     // 1/4096

// ---------------- c2h[c] = -0.5 * ||vocab[c]||^2 ----------------
__global__ __launch_bounds__(256) void c2_kernel(const float* __restrict__ vocab,
                                                 float* __restrict__ c2h) {
    int c = blockIdx.x * 256 + threadIdx.x;
    const float4* row = (const float4*)(vocab + (size_t)c * DIM);
    float a0 = 0.f, a1 = 0.f, a2 = 0.f, a3 = 0.f;
#pragma unroll
    for (int k = 0; k < DIM / 4; ++k) {
        float4 v = row[k];
        a0 = fmaf(v.x, v.x, a0); a1 = fmaf(v.y, v.y, a1);
        a2 = fmaf(v.z, v.z, a2); a3 = fmaf(v.w, v.w, a3);
    }
    c2h[c] = -0.5f * ((a0 + a1) + (a2 + a3));
}

// ---------------- split fp32 -> f16 hi + f16 lo*4096 ----------------
__global__ __launch_bounds__(256) void split_kernel(const float* __restrict__ src,
                                                    _Float16* __restrict__ hi,
                                                    _Float16* __restrict__ lo) {
    int t = blockIdx.x * 256 + threadIdx.x;     // one thread per 8 elements
    const float4* s = (const float4*)(src + (size_t)t * 8);
    float4 f0 = s[0], f1 = s[1];
    float x[8] = {f0.x, f0.y, f0.z, f0.w, f1.x, f1.y, f1.z, f1.w};
    half8 h, l;
#pragma unroll
    for (int j = 0; j < 8; ++j) {
        _Float16 hh = (_Float16)x[j];
        h[j] = hh;
        l[j] = (_Float16)((x[j] - (float)hh) * LO_SCALE);   // scaled lo: stays normal
    }
    *(half8*)(hi + (size_t)t * 8) = h;
    *(half8*)(lo + (size_t)t * 8) = l;
}

// async global->LDS; LDS dest = uniform base + lane*size (implicit). size literal.
__device__ __forceinline__ void gload_lds16(const void* g, void* lds_dst) {
    __builtin_amdgcn_global_load_lds(
        (const __attribute__((address_space(1))) void*)g,
        (__attribute__((address_space(3))) void*)lds_dst, 16, 0, 0);
}
__device__ __forceinline__ void gload_lds4(const void* g, void* lds_dst) {
    __builtin_amdgcn_global_load_lds(
        (const __attribute__((address_space(1))) void*)g,
        (__attribute__((address_space(3))) void*)lds_dst, 4, 0, 0);
}

// ---------------- main: 32x32x16 MFMA GEMM + fused argmin ----------------
// r12 post-mortem: 32x32 port regressed 104->139us because per-wave ILP
// collapsed — the al accumulator was a chain of 8 DEPENDENT MFMAs (Ah.Bl and
// Al.Bh pairs back-to-back into one acc), stalling the matrix pipe at
// 2 waves/SIMD. THIS ROUND: split the cross stream into two independent
// chains alA = sum Ah.Bl, alB = sum Al.Bh; epilogue merges
// val = (alA+alB)*LO_INV + am (one extra fp32 rounding at 2^-11 of the dot —
// far below argmin gaps). Inner loop = 3 interleaved chains, consecutive
// MFMAs never share an accumulator (spacing 3 issues ~ 96 SIMD-cyc).
// Everything else identical to r12's passing kernel (layouts verified by
// absmax 0; staging vmcnt(5); setprio; NSLICE=4).
__global__ __launch_bounds__(THREADS, 2)
void argmin_mfma(const float* __restrict__ patches,
                 const _Float16* __restrict__ vhi,
                 const _Float16* __restrict__ vlo,
                 const float* __restrict__ c2g,     // holds -0.5*||c||^2
                 float* __restrict__ ws_best,
                 int*   __restrict__ ws_idx) {
    constexpr int CSLICE = VOCAB / NSLICE;
    constexpr int NCHUNK = CSLICE / CHUNK;
    // [buf0: hi 8K | lo 8K][buf1: hi 8K | lo 8K][c2 buf0 256B][c2 buf1 256B]
    __shared__ __align__(16) char smem[2 * 16384 + 2 * 256];

    const int tid   = threadIdx.x;
    const int lane  = tid & 63;
    const int w     = tid >> 6;                     // wave 0..3
    const int slice = blockIdx.x & (NSLICE - 1);
    const int qg    = blockIdx.x / NSLICE;
    const int qbase = qg * QPB + w * 32;            // this wave's 32 queries
    const int cbase = slice * CSLICE;

    const int col  = lane & 31;                     // A-row / B-col within tile
    const int ksel = lane >> 5;                     // k-half selector (8 dims)

    // ---- load + split this wave's A fragments (queries) into registers ----
    half8 Ah[4], Al[4];
#pragma unroll
    for (int kk = 0; kk < 4; ++kk) {
        const float* p = patches + (size_t)(qbase + col) * DIM + kk * 16 + ksel * 8;
        float4 f0 = *(const float4*)p;
        float4 f1 = *(const float4*)(p + 4);
        float x[8] = {f0.x, f0.y, f0.z, f0.w, f1.x, f1.y, f1.z, f1.w};
        half8 h, l;
#pragma unroll
        for (int j = 0; j < 8; ++j) {
            _Float16 hh = (_Float16)x[j];
            h[j] = hh;
            l[j] = (_Float16)((x[j] - (float)hh) * LO_SCALE);
        }
        Ah[kk] = h; Al[kk] = l;
    }

    // staging source offsets: unit u = (4j+w)*64 + lane ->
    // T=u>>8, kk=(u>>6)&3, ks=(u>>5)&1, row=u&31
    int soff[2];
#pragma unroll
    for (int j = 0; j < 2; ++j) {
        int u = (4 * j + w) * 64 + lane;
        int T = u >> 8, kk = (u >> 6) & 3, ks2 = (u >> 5) & 1, row = u & 31;
        soff[j] = (T * 32 + row) * DIM + kk * 16 + ks2 * 8;
    }
    // B-frag ds_read lane offset within a (T,kk) 1KB region
    const int rdoff = ksel * 512 + col * 16;

    // stage chunk ch into buffer buf: 2x hi + 2x lo + c2 = 5 VMEM/wave
    auto stage = [&](int ch, int buf) {
        const size_t crow = (size_t)(cbase + ch * CHUNK) * DIM;
        char* dst = smem + buf * 16384;
#pragma unroll
        for (int j = 0; j < 2; ++j) {
            gload_lds16(vhi + crow + soff[j], dst + (4 * j + w) * 1024);
            gload_lds16(vlo + crow + soff[j], dst + 8192 + (4 * j + w) * 1024);
        }
        gload_lds4(c2g + cbase + ch * CHUNK + lane, smem + 32768 + buf * 256);
    };

    float best[16];
    int   bidx[16];
#pragma unroll
    for (int r = 0; r < 16; ++r) { best[r] = -FLT_MAX; bidx[r] = 0; }

    stage(0, 0);

    for (int ch = 0; ch < NCHUNK; ++ch) {
        const int cur = ch & 1;
        if (ch + 1 < NCHUNK) {
            stage(ch + 1, cur ^ 1);
            asm volatile("s_waitcnt vmcnt(5)" ::: "memory");   // ch landed; ch+1 in flight
        } else {
            asm volatile("s_waitcnt vmcnt(0)" ::: "memory");
        }
        __builtin_amdgcn_s_barrier();

        const char*  hib = smem + cur * 16384;
        const char*  lob = hib + 8192;
        const float* c2b = (const float*)(smem + 32768 + cur * 256);
        const int cb = cbase + ch * CHUNK;

#pragma unroll
        for (int T = 0; T < 2; ++T) {
            half8 Bh[4], Bl[4];
#pragma unroll
            for (int kk = 0; kk < 4; ++kk) {
                Bh[kk] = *(const half8*)(hib + T * 4096 + kk * 1024 + rdoff);
                Bl[kk] = *(const half8*)(lob + T * 4096 + kk * 1024 + rdoff);
            }
            const float c2h = c2b[T * 32 + col];    // -0.5*||c||^2 (LDS)
            const int  cidx = cb + T * 32 + col;

            f32x16 am, alA, alB;
#pragma unroll
            for (int r = 0; r < 16; ++r) { am[r] = c2h; alA[r] = 0.f; alB[r] = 0.f; }

            __builtin_amdgcn_s_setprio(1);
            // 3 INDEPENDENT chains: am = Ah.Bh (+c2 seed); alA = Ah.Bl; alB = Al.Bh
            // consecutive MFMAs never share an accumulator -> no dep stalls
#pragma unroll
            for (int kk = 0; kk < 4; ++kk) {
                am  = __builtin_amdgcn_mfma_f32_32x32x16_f16(Ah[kk], Bh[kk], am,  0, 0, 0);
                alA = __builtin_amdgcn_mfma_f32_32x32x16_f16(Ah[kk], Bl[kk], alA, 0, 0, 0);
                alB = __builtin_amdgcn_mfma_f32_32x32x16_f16(Al[kk], Bh[kk], alB, 0, 0, 0);
            }
            __builtin_amdgcn_s_setprio(0);

#pragma unroll
            for (int r = 0; r < 16; ++r) {
                float val = fmaf(alA[r] + alB[r], LO_INV, am[r]);   // dot - c2/2
                // argmax == argmin of distance; strict > keeps FIRST (lowest c) on ties
                if (val > best[r]) { best[r] = val; bidx[r] = cidx; }
            }
        }
        __builtin_amdgcn_s_barrier();   // all reads of buf[cur] done before overwrite
    }

    // ---- butterfly argmax-merge across the 32 column-lanes of each half ----
#pragma unroll
    for (int r = 0; r < 16; ++r) {
        float b = best[r]; int bi = bidx[r];
#pragma unroll
        for (int d = 1; d < 32; d <<= 1) {
            float ob = __shfl_xor(b, d, 64);
            int   oi = __shfl_xor(bi, d, 64);
            if (ob > b || (ob == b && oi < bi)) { b = ob; bi = oi; }
        }
        best[r] = b; bidx[r] = bi;
    }

    if (col == 0) {     // lanes 0 and 32 each hold 16 rows of their half
#pragma unroll
        for (int r = 0; r < 16; ++r) {
            int q = qbase + (r & 3) + 8 * (r >> 2) + 4 * ksel;
            ws_best[(size_t)slice * NQ + q] = best[r];
            ws_idx [(size_t)slice * NQ + q] = bidx[r];
        }
    }
}

// ---------------- merge slices (max of val, lower index on ties) ----------------
__global__ __launch_bounds__(256) void merge_kernel(const float* __restrict__ ws_best,
                                                    const int* __restrict__ ws_idx,
                                                    int* __restrict__ out) {
    int q = blockIdx.x * 256 + threadIdx.x;
    float b = ws_best[q]; int bi = ws_idx[q];
#pragma unroll
    for (int s = 1; s < NSLICE; ++s) {
        float v = ws_best[(size_t)s * NQ + q];
        int  vi = ws_idx[(size_t)s * NQ + q];
        if (v > b || (v == b && vi < bi)) { b = v; bi = vi; }
    }
    out[q] = bi;
}

extern "C" void kernel_launch(void* const* d_in, const int* in_sizes, int n_in,
                              void* d_out, int out_size, void* d_ws, size_t ws_size,
                              hipStream_t stream) {
    const float* patches = (const float*)d_in[0];   // [32768][64] fp32
    const float* vocab   = (const float*)d_in[1];   // [8192][64] fp32
    char* ws = (char*)d_ws;
    float*    c2    = (float*)ws;                                   // 32 KB
    _Float16* vhi   = (_Float16*)(ws + 32768);                      // 1 MB
    _Float16* vlo   = (_Float16*)(ws + 32768 + 1048576);            // 1 MB
    float*    wbest = (float*)(ws + 32768 + 2097152);               // 512 KB
    int*      widx  = (int*)  (ws + 32768 + 2097152 + 524288);      // 512 KB
    int* out = (int*)d_out;

    c2_kernel   <<<VOCAB / 256, 256, 0, stream>>>(vocab, c2);
    split_kernel<<<(VOCAB * DIM / 8) / 256, 256, 0, stream>>>(vocab, vhi, vlo);
    argmin_mfma <<<(NQ / QPB) * NSLICE, THREADS, 0, stream>>>(patches, vhi, vlo, c2, wbest, widx);
    merge_kernel<<<NQ / 256, 256, 0, stream>>>(wbest, widx, out);
}

// Round 14
// 112.838 us; speedup vs baseline: 1.2645x; 1.2645x over previous
//
#include <hip/hip_runtime.h>
#include <float.h>

#define VOCAB 8192
#define DIM 64
#define NQ 32768
#define CHUNK 64                    // centroids staged per LDS buffer
#define THREADS 256
#define QPB 256                     // queries per block (64 per wave, t=4)
#define NSLICE 4

typedef __attribute__((ext_vector_type(8))) _Float16 half8;
typedef __attribute__((ext_vector_type(4))) float f32x4;

#define LO_SCALE 4096.0f
#define LO_INV   2.44140625e-4f     // 1/4096

// ---------------- c2h[c] = -0.5 * ||vocab[c]||^2 ----------------
__global__ __launch_bounds__(256) void c2_kernel(const float* __restrict__ vocab,
                                                 float* __restrict__ c2h) {
    int c = blockIdx.x * 256 + threadIdx.x;
    const float4* row = (const float4*)(vocab + (size_t)c * DIM);
    float a0 = 0.f, a1 = 0.f, a2 = 0.f, a3 = 0.f;
#pragma unroll
    for (int k = 0; k < DIM / 4; ++k) {
        float4 v = row[k];
        a0 = fmaf(v.x, v.x, a0); a1 = fmaf(v.y, v.y, a1);
        a2 = fmaf(v.z, v.z, a2); a3 = fmaf(v.w, v.w, a3);
    }
    c2h[c] = -0.5f * ((a0 + a1) + (a2 + a3));
}

// ---------------- split fp32 -> f16 hi + f16 lo*4096 ----------------
__global__ __launch_bounds__(256) void split_kernel(const float* __restrict__ src,
                                                    _Float16* __restrict__ hi,
                                                    _Float16* __restrict__ lo) {
    int t = blockIdx.x * 256 + threadIdx.x;     // one thread per 8 elements
    const float4* s = (const float4*)(src + (size_t)t * 8);
    float4 f0 = s[0], f1 = s[1];
    float x[8] = {f0.x, f0.y, f0.z, f0.w, f1.x, f1.y, f1.z, f1.w};
    half8 h, l;
#pragma unroll
    for (int j = 0; j < 8; ++j) {
        _Float16 hh = (_Float16)x[j];
        h[j] = hh;
        l[j] = (_Float16)((x[j] - (float)hh) * LO_SCALE);   // scaled lo: stays normal
    }
    *(half8*)(hi + (size_t)t * 8) = h;
    *(half8*)(lo + (size_t)t * 8) = l;
}

// async global->LDS; LDS dest = uniform base + lane*size (implicit). size literal.
__device__ __forceinline__ void gload_lds16(const void* g, void* lds_dst) {
    __builtin_amdgcn_global_load_lds(
        (const __attribute__((address_space(1))) void*)g,
        (__attribute__((address_space(3))) void*)lds_dst, 16, 0, 0);
}
__device__ __forceinline__ void gload_lds4(const void* g, void* lds_dst) {
    __builtin_amdgcn_global_load_lds(
        (const __attribute__((address_space(1))) void*)g,
        (__attribute__((address_space(3))) void*)lds_dst, 4, 0, 0);
}

// ---------------- main: MFMA GEMM + fused argmin (argmax of dot - c2/2) ----------------
// Body = r8's proven kernel (16x16x32, t=4, 124 VGPR, counted vmcnt(5),
// setprio; 104us best-so-far). r12/r13 falsified the 32x32 route (B-frag
// liveness can't fit 128-reg budget -> serialized lgkm waits).
//
// THIS ROUND: triple-buffer LDS, ONE barrier per chunk (was 2).
//   stage(0,b0); stage(1,b1);
//   for ch: { vmcnt(5) [ch landed, ch+1 in flight]; s_barrier;
//             stage(ch+2,(ch+2)%3); compute(ch%3); }
// Safety: barrier at iter ch => all waves finished compute ch-1 =>
// buf[(ch+2)%3] == buf[(ch-1)%3] is idle when stage overwrites it.
// vmcnt(5) semantics proven in r8 (m135: waits oldest-first). Barriers
// 64 -> 32; prefetch window widens to ~2 compute phases. LDS 49.9KB
// -> still 2 blocks/CU at the hint=2 cap.
__global__ __launch_bounds__(THREADS, 2)
void argmin_mfma(const float* __restrict__ patches,
                 const _Float16* __restrict__ vhi,
                 const _Float16* __restrict__ vlo,
                 const float* __restrict__ c2g,     // holds -0.5*||c||^2
                 float* __restrict__ ws_best,
                 int*   __restrict__ ws_idx) {
    constexpr int CSLICE = VOCAB / NSLICE;
    constexpr int NCHUNK = CSLICE / CHUNK;
    // [buf0|buf1|buf2: hi 8K + lo 8K each][c2: 3 x 256B]
    __shared__ __align__(16) char smem[3 * 16384 + 3 * 256];

    const int tid   = threadIdx.x;
    const int lane  = tid & 63;
    const int w     = tid >> 6;                     // wave 0..3
    const int slice = blockIdx.x & (NSLICE - 1);    // XCD-aligned vocab slice
    const int qg    = blockIdx.x / NSLICE;
    const int qbase = qg * QPB + w * 64;            // this wave's 64 queries
    const int cbase = slice * CSLICE;

    // ---- load + split this wave's A fragments (queries) into registers ----
    const int arow = lane & 15;                 // query row within 16-tile
    const int akc  = lane >> 4;                 // k-chunk 0..3 (8 elems each)
    half8 Ah[4][2], Al[4][2];
#pragma unroll
    for (int t = 0; t < 4; ++t)
#pragma unroll
        for (int ks = 0; ks < 2; ++ks) {
            const float* p = patches + (size_t)(qbase + t * 16 + arow) * DIM
                           + ks * 32 + akc * 8;
            float4 f0 = *(const float4*)p;
            float4 f1 = *(const float4*)(p + 4);
            float x[8] = {f0.x, f0.y, f0.z, f0.w, f1.x, f1.y, f1.z, f1.w};
            half8 h, l;
#pragma unroll
            for (int j = 0; j < 8; ++j) {
                _Float16 hh = (_Float16)x[j];
                h[j] = hh;
                l[j] = (_Float16)((x[j] - (float)hh) * LO_SCALE);
            }
            Ah[t][ks] = h; Al[t][ks] = l;
        }

    // staging source offset (elems): row = (lane>>3), col16' = (lane&7)^(lane>>3)
    const int s_srcoff = ((lane >> 3) * DIM) + (((lane & 7) ^ (lane >> 3)) * 8);
    // frag ds_read byte offsets: row fr, swizzled k-chunk
    const int fr = lane & 15;
    const int fx = fr & 7;
    const int b_off0 = fr * 128 + (((0 * 4 + akc) ^ fx) * 16);   // kstep 0
    const int b_off1 = fr * 128 + (((1 * 4 + akc) ^ fx) * 16);   // kstep 1

    // stage chunk ch into buffer buf (0..2): 4x 1KB hi/lo + 256B c2 = 5 VMEM/wave
    auto stage = [&](int ch, int buf) {
        const size_t crow = (size_t)(cbase + ch * CHUNK) * DIM;
        char* dst = smem + buf * 16384;
#pragma unroll
        for (int j = 0; j < 2; ++j) {
            int r0 = (w + 4 * j) * 8;           // 8 rows = 1KB per instr
            gload_lds16(vhi + crow + (size_t)r0 * DIM + s_srcoff, dst + r0 * 128);
            gload_lds16(vlo + crow + (size_t)r0 * DIM + s_srcoff, dst + 8192 + r0 * 128);
        }
        // all 4 waves duplicate the same 256B c2 row (identical data, benign)
        gload_lds4(c2g + cbase + ch * CHUNK + lane, smem + 3 * 16384 + buf * 256);
    };

    float best[4][4];
    int   bidx[4][4];
#pragma unroll
    for (int t = 0; t < 4; ++t)
#pragma unroll
        for (int j = 0; j < 4; ++j) { best[t][j] = -FLT_MAX; bidx[t][j] = 0; }

    stage(0, 0);
    if (NCHUNK > 1) stage(1, 1);

    for (int ch = 0; ch < NCHUNK; ++ch) {
        const int cur = ch % 3;
        if (ch + 1 < NCHUNK) {
            // outstanding = ch's 5 + (ch+1)'s 5; wait lands the 5 oldest (= ch)
            asm volatile("s_waitcnt vmcnt(5)" ::: "memory");
        } else {
            asm volatile("s_waitcnt vmcnt(0)" ::: "memory");
        }
        __builtin_amdgcn_s_barrier();   // all waves: ch staged, compute ch-1 done
        if (ch + 2 < NCHUNK) stage(ch + 2, (ch + 2) % 3);   // overwrites buf[(ch-1)%3]

        const char*  hib = smem + cur * 16384;
        const char*  lob = hib + 8192;
        const float* c2b = (const float*)(smem + 3 * 16384 + cur * 256);
        const int cb = cbase + ch * CHUNK;

#pragma unroll
        for (int nt = 0; nt < 4; ++nt) {
            const int rt = nt * 16;
            half8 Bh0 = *(const half8*)(hib + rt * 128 + b_off0);
            half8 Bh1 = *(const half8*)(hib + rt * 128 + b_off1);
            half8 Bl0 = *(const half8*)(lob + rt * 128 + b_off0);
            half8 Bl1 = *(const half8*)(lob + rt * 128 + b_off1);
            const float c2h = c2b[rt + fr];         // -0.5*||c||^2 (LDS)
            const int  cidx = cb + rt + fr;
            __builtin_amdgcn_s_setprio(1);
#pragma unroll
            for (int t = 0; t < 4; ++t) {
                f32x4 am = {c2h, c2h, c2h, c2h};    // hi*hi, seeded with -c2/2
                f32x4 al = {0.f, 0.f, 0.f, 0.f};    // cross terms, scale 4096
                am = __builtin_amdgcn_mfma_f32_16x16x32_f16(Ah[t][0], Bh0, am, 0, 0, 0);
                am = __builtin_amdgcn_mfma_f32_16x16x32_f16(Ah[t][1], Bh1, am, 0, 0, 0);
                al = __builtin_amdgcn_mfma_f32_16x16x32_f16(Ah[t][0], Bl0, al, 0, 0, 0);
                al = __builtin_amdgcn_mfma_f32_16x16x32_f16(Ah[t][1], Bl1, al, 0, 0, 0);
                al = __builtin_amdgcn_mfma_f32_16x16x32_f16(Al[t][0], Bh0, al, 0, 0, 0);
                al = __builtin_amdgcn_mfma_f32_16x16x32_f16(Al[t][1], Bh1, al, 0, 0, 0);
#pragma unroll
                for (int j = 0; j < 4; ++j) {
                    float val = fmaf(al[j], LO_INV, am[j]);     // dot - c2/2
                    // argmax == argmin of distance; strict > keeps FIRST (lowest c) on ties
                    if (val > best[t][j]) { best[t][j] = val; bidx[t][j] = cidx; }
                }
            }
            __builtin_amdgcn_s_setprio(0);
        }
        // no second barrier: next iteration's start-barrier guards buffer reuse
    }

    // ---- butterfly argmax-merge across the 16 column-lanes of each row-group ----
#pragma unroll
    for (int t = 0; t < 4; ++t)
#pragma unroll
        for (int j = 0; j < 4; ++j) {
            float b = best[t][j]; int bi = bidx[t][j];
#pragma unroll
            for (int d = 1; d < 16; d <<= 1) {
                float ob = __shfl_xor(b, d, 64);
                int   oi = __shfl_xor(bi, d, 64);
                if (ob > b || (ob == b && oi < bi)) { b = ob; bi = oi; }
            }
            best[t][j] = b; bidx[t][j] = bi;
        }

    if ((lane & 15) == 0) {
        const int rg = lane >> 4;
#pragma unroll
        for (int t = 0; t < 4; ++t)
#pragma unroll
            for (int j = 0; j < 4; ++j) {
                int q = qbase + t * 16 + rg * 4 + j;
                ws_best[(size_t)slice * NQ + q] = best[t][j];
                ws_idx [(size_t)slice * NQ + q] = bidx[t][j];
            }
    }
}

// ---------------- merge slices (max of val, lower index on ties) ----------------
__global__ __launch_bounds__(256) void merge_kernel(const float* __restrict__ ws_best,
                                                    const int* __restrict__ ws_idx,
                                                    int* __restrict__ out) {
    int q = blockIdx.x * 256 + threadIdx.x;
    float b = ws_best[q]; int bi = ws_idx[q];
#pragma unroll
    for (int s = 1; s < NSLICE; ++s) {
        float v = ws_best[(size_t)s * NQ + q];
        int  vi = ws_idx[(size_t)s * NQ + q];
        if (v > b || (v == b && vi < bi)) { b = v; bi = vi; }
    }
    out[q] = bi;
}

extern "C" void kernel_launch(void* const* d_in, const int* in_sizes, int n_in,
                              void* d_out, int out_size, void* d_ws, size_t ws_size,
                              hipStream_t stream) {
    const float* patches = (const float*)d_in[0];   // [32768][64] fp32
    const float* vocab   = (const float*)d_in[1];   // [8192][64] fp32
    char* ws = (char*)d_ws;
    float*    c2    = (float*)ws;                                   // 32 KB
    _Float16* vhi   = (_Float16*)(ws + 32768);                      // 1 MB
    _Float16* vlo   = (_Float16*)(ws + 32768 + 1048576);            // 1 MB
    float*    wbest = (float*)(ws + 32768 + 2097152);               // 512 KB
    int*      widx  = (int*)  (ws + 32768 + 2097152 + 524288);      // 512 KB
    int* out = (int*)d_out;

    c2_kernel   <<<VOCAB / 256, 256, 0, stream>>>(vocab, c2);
    split_kernel<<<(VOCAB * DIM / 8) / 256, 256, 0, stream>>>(vocab, vhi, vlo);
    argmin_mfma <<<(NQ / QPB) * NSLICE, THREADS, 0, stream>>>(patches, vhi, vlo, c2, wbest, widx);
    merge_kernel<<<NQ / 256, 256, 0, stream>>>(wbest, widx, out);
}